// Round 1
// baseline (343.608 us; speedup 1.0000x reference)
//
#include <hip/hip_runtime.h>
#include <hip/hip_bf16.h>

#define BC 2048
#define RR 16
#define DM 512
#define NREG (BC * RR)                    // 32768 regions
#define XPATCH ((size_t)BC * 64 * DM)     // 67,108,864 floats

// One block = one region (bc, r). 256 threads.
// Phase A (wave 0): classifier -> argmax expert -> LDS + cls_pred store.
// Phase B (all): expert embedding (distinct dots only) + sinusoid PE + store.
__global__ __launch_bounds__(256) void ape_fused(
    const float* __restrict__ x,
    const float* __restrict__ gumbel,
    const float* __restrict__ w1,
    const float* __restrict__ b1,
    const float* __restrict__ w2,
    const float* __restrict__ b2,
    const float* __restrict__ w8,
    const float* __restrict__ w16,
    const float* __restrict__ w32,
    float* __restrict__ out)
{
    const int rid = blockIdx.x;           // 0..32767
    const int bc  = rid >> 4;
    const int r   = rid & 15;
    const int tid = threadIdx.x;

    __shared__ float xs[32];
    __shared__ int sidx;

    if (tid < 32) xs[tid] = x[(size_t)bc * 512 + r * 32 + tid];
    __syncthreads();

    // ---- Phase A: classifier (wave 0, lane k = hidden unit k) ----
    if (tid < 64) {
        float acc = b1[tid];
        #pragma unroll
        for (int q = 0; q < 32; ++q)
            acc = fmaf(xs[q], w1[q * 64 + tid], acc);
        float h = fmaxf(acc, 0.f);
        float p0 = h * w2[tid * 3 + 0];
        float p1 = h * w2[tid * 3 + 1];
        float p2 = h * w2[tid * 3 + 2];
        #pragma unroll
        for (int off = 32; off; off >>= 1) {
            p0 += __shfl_down(p0, off, 64);
            p1 += __shfl_down(p1, off, 64);
            p2 += __shfl_down(p2, off, 64);
        }
        if (tid == 0) {
            const float* g = gumbel + rid * 3;
            float s0 = p0 + b2[0] + g[0];
            float s1 = p1 + b2[1] + g[1];
            float s2 = p2 + b2[2] + g[2];
            int best = 0; float bs = s0;
            if (s1 > bs) { bs = s1; best = 1; }
            if (s2 > bs) { best = 2; }
            sidx = best;
            // all_cls_pred = cls_pred.T.reshape(-1) -> index r*BC + bc
            out[XPATCH + (size_t)r * BC + bc] = (float)best;
        }
    }
    __syncthreads();

    // ---- Phase B: expert embedding + PE ----
    const int e  = sidx;                  // block-uniform
    const int d0 = tid * 2;               // each thread owns (d0, d0+1)

    auto dot = [&](const float* __restrict__ w, int xoff, int len) -> float2 {
        float2 acc = make_float2(0.f, 0.f);
        #pragma unroll
        for (int q = 0; q < len; ++q) {
            float2 wv = *reinterpret_cast<const float2*>(w + (size_t)q * DM + d0);
            float xv = xs[xoff + q];
            acc.x = fmaf(xv, wv.x, acc.x);
            acc.y = fmaf(xv, wv.y, acc.y);
        }
        return acc;
    };

    float2 a0, a1, a2, a3;                // accumulators per t = 0..3
    if (e == 0) {
        // p=8: sel = [0,1,2,3] -> 4 distinct dots of len 8
        a0 = dot(w8, 0, 8);
        a1 = dot(w8, 8, 8);
        a2 = dot(w8, 16, 8);
        a3 = dot(w8, 24, 8);
    } else if (e == 1) {
        // p=16: sel = [0,0,0,1] -> 2 distinct dots of len 16
        a0 = dot(w16, 0, 16);
        a3 = dot(w16, 16, 16);
        a1 = a0; a2 = a0;
    } else {
        // p=32: sel = [0,0,0,0] -> 1 distinct dot of len 32
        a0 = dot(w32, 0, 32);
        a1 = a0; a2 = a0; a3 = a0;
    }

    // PE: pe[pos, 2j]   = sin(pos * div_j), pe[pos, 2j+1] = cos(pos * div_j)
    // div_j = exp(-j * ln(10000)/256), j = d0/2 = tid
    const float div = __expf((float)tid * (-9.210340371976184f / 256.0f));
    const int pos0 = r * 4;
    size_t obase = ((size_t)(bc * 64 + pos0)) * DM + d0;

    float2 av[4] = {a0, a1, a2, a3};
    #pragma unroll
    for (int t = 0; t < 4; ++t) {
        float sv, cv;
        __sincosf((float)(pos0 + t) * div, &sv, &cv);
        float2 o;
        o.x = av[t].x + sv;
        o.y = av[t].y + cv;
        *reinterpret_cast<float2*>(out + obase + (size_t)t * DM) = o;
    }
}

extern "C" void kernel_launch(void* const* d_in, const int* in_sizes, int n_in,
                              void* d_out, int out_size, void* d_ws, size_t ws_size,
                              hipStream_t stream) {
    const float* x      = (const float*)d_in[0];
    const float* gumbel = (const float*)d_in[1];
    const float* w1     = (const float*)d_in[2];
    const float* b1     = (const float*)d_in[3];
    const float* w2     = (const float*)d_in[4];
    const float* b2     = (const float*)d_in[5];
    const float* w8     = (const float*)d_in[6];
    const float* w16    = (const float*)d_in[7];
    const float* w32    = (const float*)d_in[8];
    float* out = (float*)d_out;

    ape_fused<<<NREG, 256, 0, stream>>>(x, gumbel, w1, b1, w2, b2, w8, w16, w32, out);
}

// Round 2
// 302.110 us; speedup vs baseline: 1.1374x; 1.1374x over previous
//
#include <hip/hip_runtime.h>
#include <hip/hip_bf16.h>

#define DM 512
#define BCN 2048
#define NROW 56                            // 8 (w8) + 16 (w16) + 32 (w32)
#define XPATCH ((size_t)BCN * 64 * DM)     // 67,108,864 floats

__device__ __forceinline__ unsigned pack_bf16(float a, float b) {
    __hip_bfloat162 h = __float22bfloat162_rn(make_float2(a, b));
    return *reinterpret_cast<unsigned*>(&h);
}
__device__ __forceinline__ float2 unpack_bf16(unsigned p) {
    float2 r;
    r.x = __uint_as_float(p << 16);
    r.y = __uint_as_float(p & 0xffff0000u);
    return r;
}
__device__ __forceinline__ void fma4(float4& a, float xv, float2 wa, float2 wb) {
    a.x = fmaf(xv, wa.x, a.x);
    a.y = fmaf(xv, wa.y, a.y);
    a.z = fmaf(xv, wb.x, a.z);
    a.w = fmaf(xv, wb.y, a.w);
}

// One block per bc row (2048 blocks x 256 threads).
// Stage: x row (512 f32) + all expert weights (56x512 as bf16 pairs) into LDS.
// Phase A: 4 waves x 4 passes -> classifier for all 16 regions.
// Phase B: 8 passes x 2 regions; 128 threads/region, float4 columns.
__global__ __launch_bounds__(256, 2) void ape_fused(
    const float* __restrict__ x,
    const float* __restrict__ gumbel,
    const float* __restrict__ w1,
    const float* __restrict__ b1,
    const float* __restrict__ w2,
    const float* __restrict__ b2,
    const float* __restrict__ w8,
    const float* __restrict__ w16,
    const float* __restrict__ w32,
    float* __restrict__ out)
{
    __shared__ unsigned wlds[NROW * 256];  // 57344 B: row-major, 256 bf16-pairs/row
    __shared__ float    xs[DM];            // 2048 B
    __shared__ int      eidx[16];

    const int bc  = blockIdx.x;
    const int tid = threadIdx.x;

    // ---- stage x row ----
    if (tid < 128)
        reinterpret_cast<float4*>(xs)[tid] =
            reinterpret_cast<const float4*>(x + (size_t)bc * DM)[tid];

    // ---- stage weights: rows 0..7 = w8, 8..23 = w16, 24..55 = w32 ----
    #pragma unroll
    for (int it = 0; it < 28; ++it) {
        int f4   = it * 256 + tid;         // float4 index 0..7167
        int row  = f4 >> 7;                // 128 float4 per row
        int col4 = f4 & 127;
        const float* src = (row < 8)  ? (w8  + (size_t)row * DM)
                         : (row < 24) ? (w16 + (size_t)(row - 8) * DM)
                                      : (w32 + (size_t)(row - 24) * DM);
        float4 v = reinterpret_cast<const float4*>(src)[col4];
        uint2 pkd = make_uint2(pack_bf16(v.x, v.y), pack_bf16(v.z, v.w));
        reinterpret_cast<uint2*>(wlds)[row * 128 + col4] = pkd;
    }
    __syncthreads();

    // ---- Phase A: classifier (fp32, exact same math as before) ----
    {
        const int lane = tid & 63;
        const int wv   = tid >> 6;
        float w1r[32];
        #pragma unroll
        for (int q = 0; q < 32; ++q) w1r[q] = w1[q * 64 + lane];
        const float w2r0 = w2[lane * 3 + 0];
        const float w2r1 = w2[lane * 3 + 1];
        const float w2r2 = w2[lane * 3 + 2];
        const float b1r  = b1[lane];

        float hh[4];
        #pragma unroll
        for (int p = 0; p < 4; ++p) {
            const int rr = p * 4 + wv;
            const float* xr = xs + rr * 32;
            float a = b1r;
            #pragma unroll
            for (int q = 0; q < 32; ++q) a = fmaf(xr[q], w1r[q], a);
            hh[p] = fmaxf(a, 0.f);
        }
        #pragma unroll
        for (int p = 0; p < 4; ++p) {
            float p0 = hh[p] * w2r0, p1 = hh[p] * w2r1, p2 = hh[p] * w2r2;
            #pragma unroll
            for (int off = 32; off; off >>= 1) {
                p0 += __shfl_down(p0, off, 64);
                p1 += __shfl_down(p1, off, 64);
                p2 += __shfl_down(p2, off, 64);
            }
            if (lane == 0) {
                const int rr = p * 4 + wv;
                const float* g = gumbel + ((size_t)bc * 16 + rr) * 3;
                float s0 = p0 + b2[0] + g[0];
                float s1 = p1 + b2[1] + g[1];
                float s2 = p2 + b2[2] + g[2];
                int best = 0; float bs = s0;
                if (s1 > bs) { bs = s1; best = 1; }
                if (s2 > bs) { best = 2; }
                eidx[rr] = best;
                out[XPATCH + (size_t)rr * BCN + bc] = (float)best;
            }
        }
    }
    __syncthreads();

    // ---- Phase B: expert embedding + PE ----
    const int rp = tid >> 7;               // which region of the pair (wave-uniform)
    const int cg = tid & 127;              // float4 column group
    const int c0 = cg * 4;
    const float kln = -9.210340371976184f / 256.0f;   // -ln(10000)/256
    const float dv0 = __expf((float)(cg * 2)     * kln);
    const float dv1 = __expf((float)(cg * 2 + 1) * kln);
    const uint2* wbase = reinterpret_cast<const uint2*>(wlds) + cg;

    #pragma unroll 1
    for (int p = 0; p < 8; ++p) {
        const int rr = p * 2 + rp;
        const int e  = eidx[rr];           // wave-uniform
        const int xo = rr * 32;
        float4 a0 = {0,0,0,0}, a1 = {0,0,0,0}, a2 = {0,0,0,0}, a3 = {0,0,0,0};

        if (e == 0) {                       // p=8: rows 0..7, reused 4x
            const uint2* wp = wbase;        // row 0
            #pragma unroll
            for (int q = 0; q < 8; ++q) {
                uint2 pk = wp[q * 128];
                float2 wa = unpack_bf16(pk.x), wb = unpack_bf16(pk.y);
                fma4(a0, xs[xo + q],      wa, wb);
                fma4(a1, xs[xo + 8  + q], wa, wb);
                fma4(a2, xs[xo + 16 + q], wa, wb);
                fma4(a3, xs[xo + 24 + q], wa, wb);
            }
        } else if (e == 1) {                // p=16: rows 8..23, sel=[0,0,0,1]
            const uint2* wp = wbase + 8 * 128;
            #pragma unroll
            for (int q = 0; q < 16; ++q) {
                uint2 pk = wp[q * 128];
                float2 wa = unpack_bf16(pk.x), wb = unpack_bf16(pk.y);
                fma4(a0, xs[xo + q],      wa, wb);
                fma4(a3, xs[xo + 16 + q], wa, wb);
            }
            a1 = a0; a2 = a0;
        } else {                            // p=32: rows 24..55, sel=[0,0,0,0]
            const uint2* wp = wbase + 24 * 128;
            #pragma unroll
            for (int q = 0; q < 32; ++q) {
                uint2 pk = wp[q * 128];
                float2 wa = unpack_bf16(pk.x), wb = unpack_bf16(pk.y);
                fma4(a0, xs[xo + q], wa, wb);
            }
            a1 = a0; a2 = a0; a3 = a0;
        }

        const size_t ob = ((size_t)(bc * 64 + rr * 4)) * DM + c0;
        float4 av[4] = {a0, a1, a2, a3};
        #pragma unroll
        for (int t = 0; t < 4; ++t) {
            float sv0, cv0, sv1, cv1;
            const float pos = (float)(rr * 4 + t);
            __sincosf(pos * dv0, &sv0, &cv0);
            __sincosf(pos * dv1, &sv1, &cv1);
            float4 o;
            o.x = av[t].x + sv0;
            o.y = av[t].y + cv0;
            o.z = av[t].z + sv1;
            o.w = av[t].w + cv1;
            *reinterpret_cast<float4*>(out + ob + (size_t)t * DM) = o;
        }
    }
}

extern "C" void kernel_launch(void* const* d_in, const int* in_sizes, int n_in,
                              void* d_out, int out_size, void* d_ws, size_t ws_size,
                              hipStream_t stream) {
    const float* x      = (const float*)d_in[0];
    const float* gumbel = (const float*)d_in[1];
    const float* w1     = (const float*)d_in[2];
    const float* b1     = (const float*)d_in[3];
    const float* w2     = (const float*)d_in[4];
    const float* b2     = (const float*)d_in[5];
    const float* w8     = (const float*)d_in[6];
    const float* w16    = (const float*)d_in[7];
    const float* w32    = (const float*)d_in[8];
    float* out = (float*)d_out;

    ape_fused<<<BCN, 256, 0, stream>>>(x, gumbel, w1, b1, w2, b2, w8, w16, w32, out);
}

// Round 3
// 298.771 us; speedup vs baseline: 1.1501x; 1.0112x over previous
//
#include <hip/hip_runtime.h>
#include <hip/hip_bf16.h>

#define DM 512
#define BCN 2048
#define XPATCH ((size_t)BCN * 64 * DM)     // 67,108,864 floats

__device__ __forceinline__ unsigned pack_bf16(float a, float b) {
    __hip_bfloat162 h = __float22bfloat162_rn(make_float2(a, b));
    return *reinterpret_cast<unsigned*>(&h);
}
__device__ __forceinline__ float2 unpack_bf16(unsigned p) {
    float2 r;
    r.x = __uint_as_float(p << 16);
    r.y = __uint_as_float(p & 0xffff0000u);
    return r;
}
__device__ __forceinline__ void fma4p(float4& a, float xv, float2 wa, float2 wb) {
    a.x = fmaf(xv, wa.x, a.x);
    a.y = fmaf(xv, wa.y, a.y);
    a.z = fmaf(xv, wb.x, a.z);
    a.w = fmaf(xv, wb.y, a.w);
}
__device__ __forceinline__ void fma4f(float4& a, float xv, float4 w) {
    a.x = fmaf(xv, w.x, a.x);
    a.y = fmaf(xv, w.y, a.y);
    a.z = fmaf(xv, w.z, a.z);
    a.w = fmaf(xv, w.w, a.w);
}

// One block per bc row (2048 blocks x 256 threads), 4 blocks/CU.
// LDS: only w32 staged (bf16 pairs, 32 KB) + x row + eidx  => ~34.5 KB.
// w8/w16 read directly from global (L2-hot, coalesced float4).
__global__ __launch_bounds__(256, 4) void ape_fused(
    const float* __restrict__ x,
    const float* __restrict__ gumbel,
    const float* __restrict__ w1,
    const float* __restrict__ b1,
    const float* __restrict__ w2,
    const float* __restrict__ b2,
    const float* __restrict__ w8,
    const float* __restrict__ w16,
    const float* __restrict__ w32,
    float* __restrict__ out)
{
    __shared__ unsigned w32s[32 * 256];    // 32 KB: 32 rows x 256 bf16-pairs
    __shared__ float    xs[DM];            // 2 KB
    __shared__ int      eidx[16];

    const int bc  = blockIdx.x;
    const int tid = threadIdx.x;

    // ---- stage x row (first 128 threads) ----
    if (tid < 128)
        reinterpret_cast<float4*>(xs)[tid] =
            reinterpret_cast<const float4*>(x + (size_t)bc * DM)[tid];

    // ---- stage w32 -> LDS bf16 (all threads, 16 float4 each) ----
    #pragma unroll
    for (int it = 0; it < 16; ++it) {
        int f4   = it * 256 + tid;         // 0..4095
        int row  = f4 >> 7;
        int col4 = f4 & 127;
        float4 v = reinterpret_cast<const float4*>(w32 + (size_t)row * DM)[col4];
        reinterpret_cast<uint2*>(w32s)[row * 128 + col4] =
            make_uint2(pack_bf16(v.x, v.y), pack_bf16(v.z, v.w));
    }
    __syncthreads();

    // ---- Phase A: classifier (fp32) ----
    {
        const int lane = tid & 63;
        const int wv   = tid >> 6;
        float w1r[32];
        #pragma unroll
        for (int q = 0; q < 32; ++q) w1r[q] = w1[q * 64 + lane];
        const float w2r0 = w2[lane * 3 + 0];
        const float w2r1 = w2[lane * 3 + 1];
        const float w2r2 = w2[lane * 3 + 2];
        const float b1r  = b1[lane];

        #pragma unroll
        for (int p = 0; p < 4; ++p) {
            const int rr = p * 4 + wv;
            const float* xr = xs + rr * 32;
            float a = b1r;
            #pragma unroll
            for (int q = 0; q < 32; ++q) a = fmaf(xr[q], w1r[q], a);
            float h = fmaxf(a, 0.f);
            float p0 = h * w2r0, p1 = h * w2r1, p2 = h * w2r2;
            #pragma unroll
            for (int off = 32; off; off >>= 1) {
                p0 += __shfl_down(p0, off, 64);
                p1 += __shfl_down(p1, off, 64);
                p2 += __shfl_down(p2, off, 64);
            }
            if (lane == 0) {
                const float* g = gumbel + ((size_t)bc * 16 + rr) * 3;
                float s0 = p0 + b2[0] + g[0];
                float s1 = p1 + b2[1] + g[1];
                float s2 = p2 + b2[2] + g[2];
                int best = 0; float bs = s0;
                if (s1 > bs) { bs = s1; best = 1; }
                if (s2 > bs) { best = 2; }
                eidx[rr] = best;
                out[XPATCH + (size_t)rr * BCN + bc] = (float)best;
            }
        }
    }
    __syncthreads();

    // ---- Phase B: expert embedding + PE ----
    const int rp = tid >> 7;               // which region of the pair (wave-uniform)
    const int cg = tid & 127;              // float4 column group
    const int c0 = cg * 4;
    const float kln = -9.210340371976184f / 256.0f;   // -ln(10000)/256
    const float dv0 = __expf((float)(cg * 2)     * kln);
    const float dv1 = __expf((float)(cg * 2 + 1) * kln);
    const uint2*  w32b = reinterpret_cast<const uint2*>(w32s) + cg;
    const float4* w8b  = reinterpret_cast<const float4*>(w8)  + cg;
    const float4* w16b = reinterpret_cast<const float4*>(w16) + cg;

    #pragma unroll 1
    for (int p = 0; p < 8; ++p) {
        const int rr = p * 2 + rp;
        const int e  = eidx[rr];           // wave-uniform
        const int xo = rr * 32;
        float4 a0 = {0,0,0,0}, a1 = {0,0,0,0}, a2 = {0,0,0,0}, a3 = {0,0,0,0};

        if (e == 0) {                       // p=8: 4 distinct dots of len 8 (global fp32)
            #pragma unroll
            for (int q = 0; q < 8; ++q) {
                float4 wv = w8b[q * 128];
                fma4f(a0, xs[xo + q],      wv);
                fma4f(a1, xs[xo + 8  + q], wv);
                fma4f(a2, xs[xo + 16 + q], wv);
                fma4f(a3, xs[xo + 24 + q], wv);
            }
        } else if (e == 1) {                // p=16: 2 distinct dots of len 16 (global fp32)
            #pragma unroll
            for (int q = 0; q < 16; ++q) {
                float4 wv = w16b[q * 128];
                fma4f(a0, xs[xo + q],      wv);
                fma4f(a3, xs[xo + 16 + q], wv);
            }
            a1 = a0; a2 = a0;
        } else {                            // p=32: 1 dot of len 32 (LDS bf16)
            #pragma unroll
            for (int q = 0; q < 32; ++q) {
                uint2 pk = w32b[q * 128];
                float2 wa = unpack_bf16(pk.x), wb = unpack_bf16(pk.y);
                fma4p(a0, xs[xo + q], wa, wb);
            }
            a1 = a0; a2 = a0; a3 = a0;
        }

        const size_t ob = ((size_t)(bc * 64 + rr * 4)) * DM + c0;
        float4 av[4] = {a0, a1, a2, a3};
        #pragma unroll
        for (int t = 0; t < 4; ++t) {
            float sv0, cv0, sv1, cv1;
            const float pos = (float)(rr * 4 + t);
            __sincosf(pos * dv0, &sv0, &cv0);
            __sincosf(pos * dv1, &sv1, &cv1);
            float4 o;
            o.x = av[t].x + sv0;
            o.y = av[t].y + cv0;
            o.z = av[t].z + sv1;
            o.w = av[t].w + cv1;
            *reinterpret_cast<float4*>(out + ob + (size_t)t * DM) = o;
        }
    }
}

extern "C" void kernel_launch(void* const* d_in, const int* in_sizes, int n_in,
                              void* d_out, int out_size, void* d_ws, size_t ws_size,
                              hipStream_t stream) {
    const float* x      = (const float*)d_in[0];
    const float* gumbel = (const float*)d_in[1];
    const float* w1     = (const float*)d_in[2];
    const float* b1     = (const float*)d_in[3];
    const float* w2     = (const float*)d_in[4];
    const float* b2     = (const float*)d_in[5];
    const float* w8     = (const float*)d_in[6];
    const float* w16    = (const float*)d_in[7];
    const float* w32    = (const float*)d_in[8];
    float* out = (float*)d_out;

    ape_fused<<<BCN, 256, 0, stream>>>(x, gumbel, w1, b1, w2, b2, w8, w16, w32, out);
}